// Round 1
// baseline (3847.232 us; speedup 1.0000x reference)
//
#include <hip/hip_runtime.h>

// LSS view transform: lift image features by depth distribution, splat into BEV grid.
// img  [B,C,H,W] fp32, dp [B,D,H,W] fp32, dv [D], K [B,3,3], T [B,4,4]
// out  [B,C,BEV_H,BEV_W] fp32
constexpr int IMG_H = 48, IMG_W = 160;
constexpr int BEV_H = 128, BEV_W = 128;
constexpr int C_DIM = 128, D_DIM = 64, B_DIM = 2;
constexpr float X_MIN = -51.2f, Y_MIN = -51.2f;
constexpr float RES_X = 102.4f / 128.0f;  // 0.8f
constexpr float RES_Y = 102.4f / 128.0f;

__global__ __launch_bounds__(128) void lss_scatter(
    const float* __restrict__ img,   // [B,C,H,W]
    const float* __restrict__ dp,    // [B,D,H,W]
    const float* __restrict__ dv,    // [D]
    const float* __restrict__ K,     // [B,3,3]
    const float* __restrict__ T,     // [B,4,4]
    float* __restrict__ out)         // [B,C,BEV_H,BEV_W]
{
    const int pix = blockIdx.x;                 // b*H*W + h*W + w
    const int b  = pix / (IMG_H * IMG_W);
    const int hw = pix % (IMG_H * IMG_W);
    const int h  = hw / IMG_W;
    const int w  = hw % IMG_W;
    const int c  = threadIdx.x;                 // channel 0..127

    // ---- 3x3 inverse of K[b] (adjugate; K is near-triangular, ulp-accurate) ----
    const float* Kb = K + b * 9;
    const float a00 = Kb[0], a01 = Kb[1], a02 = Kb[2];
    const float a10 = Kb[3], a11 = Kb[4], a12 = Kb[5];
    const float a20 = Kb[6], a21 = Kb[7], a22 = Kb[8];
    const float det = a00 * (a11 * a22 - a12 * a21)
                    - a01 * (a10 * a22 - a12 * a20)
                    + a02 * (a10 * a21 - a11 * a20);
    const float inv = 1.0f / det;
    const float i00 =  (a11 * a22 - a12 * a21) * inv;
    const float i01 = -(a01 * a22 - a02 * a21) * inv;
    const float i02 =  (a01 * a12 - a02 * a11) * inv;
    const float i10 = -(a10 * a22 - a12 * a20) * inv;
    const float i11 =  (a00 * a22 - a02 * a20) * inv;
    const float i12 = -(a00 * a12 - a02 * a10) * inv;
    const float i20 =  (a10 * a21 - a11 * a20) * inv;
    const float i21 = -(a00 * a21 - a01 * a20) * inv;
    const float i22 =  (a00 * a11 - a01 * a10) * inv;

    // ray = K_inv @ (w, h, 1)
    const float gx = (float)w, gy = (float)h;
    const float rx = i00 * gx + i01 * gy + i02;
    const float ry = i10 * gx + i11 * gy + i12;
    const float rz = i20 * gx + i21 * gy + i22;

    const float* Tb = T + b * 16;
    const float r00 = Tb[0], r01 = Tb[1], r02 = Tb[2],  tx = Tb[3];
    const float r10 = Tb[4], r11 = Tb[5], r12 = Tb[6],  ty = Tb[7];
    const float r20 = Tb[8], r21 = Tb[9], r22 = Tb[10], tz = Tb[11];

    // per-thread channel feature at this pixel
    const float f = img[(((size_t)b * C_DIM + c) * IMG_H + h) * IMG_W + w];

    // threads 0..63 project the 64 depth bins into LDS
    __shared__ int   s_cell[D_DIM];
    __shared__ float s_p[D_DIM];
    if (threadIdx.x < D_DIM) {
        const int d = threadIdx.x;
        const float dep = dv[d];
        const float px = dep * rx, py = dep * ry, pz = dep * rz;
        const float x = r00 * px + r01 * py + r02 * pz + tx;
        const float y = r10 * px + r11 * py + r12 * pz + ty;
        const float z = r20 * px + r21 * py + r22 * pz + tz;
        // (int) truncates toward zero == astype(int32) == torch .long()
        const int bx = (int)((x - X_MIN) / RES_X);
        const int by = (int)((y - Y_MIN) / RES_Y);
        const bool valid = (bx >= 0) && (bx < BEV_W) && (by >= 0) && (by < BEV_H) && (z > 0.0f);
        s_cell[d] = valid ? (by * BEV_W + bx) : -1;
        s_p[d]    = dp[(((size_t)b * D_DIM + d) * IMG_H + h) * IMG_W + w];
    }
    __syncthreads();

    float* outb = out + ((size_t)b * C_DIM + c) * (BEV_H * BEV_W);

    // d-loop: merge consecutive same-cell depth bins before the atomic
    int   prev = -1;
    float acc  = 0.0f;
    #pragma unroll
    for (int d = 0; d < D_DIM; ++d) {
        const int cell = s_cell[d];
        const float p  = s_p[d];
        if (cell == prev) {
            acc += p;
        } else {
            if (prev >= 0) atomicAdd(&outb[prev], f * acc);
            prev = cell;
            acc  = p;
        }
    }
    if (prev >= 0) atomicAdd(&outb[prev], f * acc);
}

extern "C" void kernel_launch(void* const* d_in, const int* in_sizes, int n_in,
                              void* d_out, int out_size, void* d_ws, size_t ws_size,
                              hipStream_t stream) {
    const float* img = (const float*)d_in[0];
    const float* dp  = (const float*)d_in[1];
    const float* dv  = (const float*)d_in[2];
    const float* K   = (const float*)d_in[3];
    const float* T   = (const float*)d_in[4];
    float* out = (float*)d_out;

    // harness poisons d_out with 0xAA before every launch -> zero it each call
    hipMemsetAsync(out, 0, (size_t)out_size * sizeof(float), stream);

    const dim3 grid(B_DIM * IMG_H * IMG_W);   // one block per (b, pixel)
    lss_scatter<<<grid, 128, 0, stream>>>(img, dp, dv, K, T, out);
}

// Round 2
// 3314.759 us; speedup vs baseline: 1.1606x; 1.1606x over previous
//
#include <hip/hip_runtime.h>

// LSS view transform, gather formulation (no output atomics).
// out[b,c,cell] = sum_{(pix,d) -> cell} img[b,c,pix] * dp[b,d,pix]
// Pipeline: transpose img -> count runs/cell -> prefix scan -> fill entries -> gather.
constexpr int IMG_H = 48, IMG_W = 160;
constexpr int HW    = IMG_H * IMG_W;          // 7680
constexpr int BEV_H = 128, BEV_W = 128;
constexpr int NCELL = BEV_H * BEV_W;          // 16384 per batch
constexpr int C_DIM = 128, D_DIM = 64, B_DIM = 2;
constexpr int NCELL_TOT = B_DIM * NCELL;      // 32768
constexpr int NPIX_TOT  = B_DIM * HW;         // 15360
constexpr int MAX_ENTRIES = NPIX_TOT * D_DIM; // 983040 worst case
constexpr float X_MIN = -51.2f, Y_MIN = -51.2f;
constexpr float RES_X = 102.4f / 128.0f;
constexpr float RES_Y = 102.4f / 128.0f;

// ---- ws layout (4-byte words) ----
constexpr size_t WS_IMG_T   = 0;                                   // float[B*HW*C]  = 1966080
constexpr size_t WS_HIST    = WS_IMG_T + (size_t)B_DIM * HW * C_DIM; // int[32768]
constexpr size_t WS_OFFS    = WS_HIST + NCELL_TOT;                 // int[32769]
constexpr size_t WS_CURSOR  = WS_OFFS + NCELL_TOT + 3;             // int[32768] (padded)
constexpr size_t WS_EPIX    = WS_CURSOR + NCELL_TOT;               // int[MAX_ENTRIES]
constexpr size_t WS_EW      = WS_EPIX + MAX_ENTRIES;               // float[MAX_ENTRIES]
constexpr size_t WS_WORDS   = WS_EW + MAX_ENTRIES;                 // ~16.1 MB

// Per-batch camera ray: K^-1 (adjugate) applied to (gx, gy, 1). Same math as the
// verified round-1 baseline (absmax 0.002 vs reference).
__device__ inline void make_ray(const float* __restrict__ K, int b, float gx, float gy,
                                float& rx, float& ry, float& rz) {
    const float* Kb = K + b * 9;
    const float a00 = Kb[0], a01 = Kb[1], a02 = Kb[2];
    const float a10 = Kb[3], a11 = Kb[4], a12 = Kb[5];
    const float a20 = Kb[6], a21 = Kb[7], a22 = Kb[8];
    const float det = a00 * (a11 * a22 - a12 * a21)
                    - a01 * (a10 * a22 - a12 * a20)
                    + a02 * (a10 * a21 - a11 * a20);
    const float inv = 1.0f / det;
    const float i00 =  (a11 * a22 - a12 * a21) * inv;
    const float i01 = -(a01 * a22 - a02 * a21) * inv;
    const float i02 =  (a01 * a12 - a02 * a11) * inv;
    const float i10 = -(a10 * a22 - a12 * a20) * inv;
    const float i11 =  (a00 * a22 - a02 * a20) * inv;
    const float i12 = -(a00 * a12 - a02 * a10) * inv;
    const float i20 =  (a10 * a21 - a11 * a20) * inv;
    const float i21 = -(a00 * a21 - a01 * a20) * inv;
    const float i22 =  (a00 * a11 - a01 * a10) * inv;
    rx = i00 * gx + i01 * gy + i02;
    ry = i10 * gx + i11 * gy + i12;
    rz = i20 * gx + i21 * gy + i22;
}

__device__ inline int project_cell(float dep, float rx, float ry, float rz,
                                   float r00, float r01, float r02, float tx,
                                   float r10, float r11, float r12, float ty,
                                   float r20, float r21, float r22, float tz) {
    const float px = dep * rx, py = dep * ry, pz = dep * rz;
    const float x = r00 * px + r01 * py + r02 * pz + tx;
    const float y = r10 * px + r11 * py + r12 * pz + ty;
    const float z = r20 * px + r21 * py + r22 * pz + tz;
    const int bx = (int)((x - X_MIN) / RES_X);   // truncate-toward-zero == astype(int32)
    const int by = (int)((y - Y_MIN) / RES_Y);
    const bool valid = (bx >= 0) && (bx < BEV_W) && (by >= 0) && (by < BEV_H) && (z > 0.0f);
    return valid ? (by * BEV_W + bx) : -1;
}

// ---- K1: tiled transpose img[b,c,pix] -> img_t[b,pix,c] ----
__global__ __launch_bounds__(256) void k_transpose(const float* __restrict__ img,
                                                   float* __restrict__ img_t) {
    __shared__ float tile[32][33];
    const int b = blockIdx.z;
    const int tx = threadIdx.x, ty = threadIdx.y;      // block (32, 8)
    const int pix0 = blockIdx.x * 32, c0 = blockIdx.y * 32;
    #pragma unroll
    for (int j = 0; j < 32; j += 8)
        tile[ty + j][tx] = img[((size_t)(b * C_DIM + c0 + ty + j)) * HW + pix0 + tx];
    __syncthreads();
    #pragma unroll
    for (int j = 0; j < 32; j += 8)
        img_t[((size_t)(b * HW + pix0 + ty + j)) * C_DIM + c0 + tx] = tile[tx][ty + j];
}

// ---- K2: count merged runs per cell ----
__global__ __launch_bounds__(256) void k_count(const float* __restrict__ dv,
                                               const float* __restrict__ K,
                                               const float* __restrict__ T,
                                               int* __restrict__ hist) {
    const int tid = blockIdx.x * 256 + threadIdx.x;
    if (tid >= NPIX_TOT) return;
    const int b = tid / HW, pix = tid % HW;
    const int h = pix / IMG_W, w = pix % IMG_W;
    float rx, ry, rz;
    make_ray(K, b, (float)w, (float)h, rx, ry, rz);
    const float* Tb = T + b * 16;
    const float r00 = Tb[0], r01 = Tb[1], r02 = Tb[2],  tx = Tb[3];
    const float r10 = Tb[4], r11 = Tb[5], r12 = Tb[6],  ty = Tb[7];
    const float r20 = Tb[8], r21 = Tb[9], r22 = Tb[10], tz = Tb[11];
    int prev = -1;
    for (int d = 0; d < D_DIM; ++d) {
        const int cell = project_cell(dv[d], rx, ry, rz,
                                      r00, r01, r02, tx, r10, r11, r12, ty, r20, r21, r22, tz);
        if (cell != prev) {
            if (prev >= 0) atomicAdd(&hist[b * NCELL + prev], 1);
            prev = cell;
        }
    }
    if (prev >= 0) atomicAdd(&hist[b * NCELL + prev], 1);
}

// ---- K3: exclusive prefix scan over hist[32768] -> offs[32769], cursor ----
__global__ __launch_bounds__(1024) void k_scan(const int* __restrict__ hist,
                                               int* __restrict__ offs,
                                               int* __restrict__ cursor) {
    __shared__ int lds[1024];
    const int t = threadIdx.x;
    int h[32];
    int s = 0;
    const int base = t * 32;
    #pragma unroll
    for (int k = 0; k < 32; ++k) { h[k] = hist[base + k]; s += h[k]; }
    lds[t] = s;
    __syncthreads();
    for (int off = 1; off < 1024; off <<= 1) {
        int v = (t >= off) ? lds[t - off] : 0;
        __syncthreads();
        lds[t] += v;
        __syncthreads();
    }
    int run = lds[t] - s;   // exclusive base for this thread's chunk
    #pragma unroll
    for (int k = 0; k < 32; ++k) {
        offs[base + k] = run;
        cursor[base + k] = run;
        run += h[k];
    }
    if (t == 1023) offs[NCELL_TOT] = lds[1023];
}

// ---- K4: fill entries (pix, merged-run weight) into per-cell buckets ----
__global__ __launch_bounds__(256) void k_fill(const float* __restrict__ dp,
                                              const float* __restrict__ dv,
                                              const float* __restrict__ K,
                                              const float* __restrict__ T,
                                              int* __restrict__ cursor,
                                              int* __restrict__ epix,
                                              float* __restrict__ ew) {
    const int tid = blockIdx.x * 256 + threadIdx.x;
    if (tid >= NPIX_TOT) return;
    const int b = tid / HW, pix = tid % HW;
    const int h = pix / IMG_W, w = pix % IMG_W;
    float rx, ry, rz;
    make_ray(K, b, (float)w, (float)h, rx, ry, rz);
    const float* Tb = T + b * 16;
    const float r00 = Tb[0], r01 = Tb[1], r02 = Tb[2],  tx = Tb[3];
    const float r10 = Tb[4], r11 = Tb[5], r12 = Tb[6],  ty = Tb[7];
    const float r20 = Tb[8], r21 = Tb[9], r22 = Tb[10], tz = Tb[11];
    int prev = -1;
    float acc = 0.0f;
    for (int d = 0; d < D_DIM; ++d) {
        const int cell = project_cell(dv[d], rx, ry, rz,
                                      r00, r01, r02, tx, r10, r11, r12, ty, r20, r21, r22, tz);
        const float p = dp[((size_t)(b * D_DIM + d)) * HW + pix];
        if (cell == prev) {
            acc += p;
        } else {
            if (prev >= 0) {
                const int slot = atomicAdd(&cursor[b * NCELL + prev], 1);
                epix[slot] = pix;
                ew[slot] = acc;
            }
            prev = cell;
            acc = p;
        }
    }
    if (prev >= 0) {
        const int slot = atomicAdd(&cursor[b * NCELL + prev], 1);
        epix[slot] = pix;
        ew[slot] = acc;
    }
}

// ---- K5: gather. Block = 16 consecutive cells, thread = channel. ----
__global__ __launch_bounds__(128) void k_gather(const float* __restrict__ img_t,
                                                const int* __restrict__ offs,
                                                const int* __restrict__ epix,
                                                const float* __restrict__ ew,
                                                float* __restrict__ out) {
    const int c = threadIdx.x;
    const int group = blockIdx.x;                 // 0 .. B*NCELL/16 - 1
    const int b = group / (NCELL / 16);
    const int localbase = (group % (NCELL / 16)) * 16;
    const float* img_b = img_t + (size_t)b * HW * C_DIM;
    float acc[16];
    #pragma unroll
    for (int j = 0; j < 16; ++j) {
        const int g = b * NCELL + localbase + j;
        const int s = offs[g], e = offs[g + 1];
        float a = 0.0f;
        for (int k = s; k < e; ++k) {
            const int pix = epix[k];            // wave-uniform
            const float wgt = ew[k];
            a = fmaf(img_b[(size_t)pix * C_DIM + c], wgt, a);
        }
        acc[j] = a;
    }
    // 16 consecutive floats per thread -> 4x float4, full-line writes.
    float* orow = out + ((size_t)(b * C_DIM + c)) * NCELL + localbase;
    #pragma unroll
    for (int j = 0; j < 4; ++j)
        reinterpret_cast<float4*>(orow)[j] = make_float4(acc[4 * j], acc[4 * j + 1],
                                                         acc[4 * j + 2], acc[4 * j + 3]);
}

extern "C" void kernel_launch(void* const* d_in, const int* in_sizes, int n_in,
                              void* d_out, int out_size, void* d_ws, size_t ws_size,
                              hipStream_t stream) {
    const float* img = (const float*)d_in[0];
    const float* dp  = (const float*)d_in[1];
    const float* dv  = (const float*)d_in[2];
    const float* K   = (const float*)d_in[3];
    const float* T   = (const float*)d_in[4];
    float* out = (float*)d_out;

    float* ws_f   = (float*)d_ws;
    float* img_t  = ws_f + WS_IMG_T;
    int*   hist   = (int*)d_ws + WS_HIST;
    int*   offs   = (int*)d_ws + WS_OFFS;
    int*   cursor = (int*)d_ws + WS_CURSOR;
    int*   epix   = (int*)d_ws + WS_EPIX;
    float* ew     = ws_f + WS_EW;

    hipMemsetAsync(hist, 0, NCELL_TOT * sizeof(int), stream);

    k_transpose<<<dim3(HW / 32, C_DIM / 32, B_DIM), dim3(32, 8), 0, stream>>>(img, img_t);
    k_count<<<(NPIX_TOT + 255) / 256, 256, 0, stream>>>(dv, K, T, hist);
    k_scan<<<1, 1024, 0, stream>>>(hist, offs, cursor);
    k_fill<<<(NPIX_TOT + 255) / 256, 256, 0, stream>>>(dp, dv, K, T, cursor, epix, ew);
    k_gather<<<B_DIM * NCELL / 16, 128, 0, stream>>>(img_t, offs, epix, ew, out);
}

// Round 3
// 642.525 us; speedup vs baseline: 5.9877x; 5.1590x over previous
//
#include <hip/hip_runtime.h>

// LSS view transform, chunked-gather formulation.
// out[b,c,cell] = sum_{(pix,d)->cell} img[b,c,pix] * dp[b,d,pix]
// Pipeline: transpose img -> count runs/cell -> prefix scan -> fill (cell-bucketed
// entries) -> chunked segmented reduction (64 entries/block, atomics only at
// segment boundaries). Fixes round-2's load imbalance (hot cells w/ 1000s of
// entries serialized in one block -> 1% occupancy).
constexpr int IMG_H = 48, IMG_W = 160;
constexpr int HW    = IMG_H * IMG_W;          // 7680
constexpr int BEV_H = 128, BEV_W = 128;
constexpr int NCELL = BEV_H * BEV_W;          // 16384 per batch
constexpr int C_DIM = 128, D_DIM = 64, B_DIM = 2;
constexpr int NCELL_TOT = B_DIM * NCELL;      // 32768
constexpr int NPIX_TOT  = B_DIM * HW;         // 15360
constexpr int MAX_ENTRIES = NPIX_TOT * D_DIM; // 983040 worst case
constexpr int CHUNK = 64;
constexpr float X_MIN = -51.2f, Y_MIN = -51.2f;
constexpr float RES_X = 102.4f / 128.0f;
constexpr float RES_Y = 102.4f / 128.0f;

// ---- ws layout (4-byte words), ~16.1 MB total ----
constexpr size_t WS_IMG_T   = 0;                                     // float[B*HW*C]
constexpr size_t WS_HIST    = WS_IMG_T + (size_t)B_DIM * HW * C_DIM; // int[32768]
constexpr size_t WS_OFFS    = WS_HIST + NCELL_TOT;                   // int[32769]
constexpr size_t WS_CURSOR  = WS_OFFS + NCELL_TOT + 3;               // int[32768]
constexpr size_t WS_EKEY    = WS_CURSOR + NCELL_TOT;                 // int[MAX_ENTRIES]
constexpr size_t WS_EW      = WS_EKEY + MAX_ENTRIES;                 // float[MAX_ENTRIES]

__device__ inline void make_ray(const float* __restrict__ K, int b, float gx, float gy,
                                float& rx, float& ry, float& rz) {
    const float* Kb = K + b * 9;
    const float a00 = Kb[0], a01 = Kb[1], a02 = Kb[2];
    const float a10 = Kb[3], a11 = Kb[4], a12 = Kb[5];
    const float a20 = Kb[6], a21 = Kb[7], a22 = Kb[8];
    const float det = a00 * (a11 * a22 - a12 * a21)
                    - a01 * (a10 * a22 - a12 * a20)
                    + a02 * (a10 * a21 - a11 * a20);
    const float inv = 1.0f / det;
    const float i00 =  (a11 * a22 - a12 * a21) * inv;
    const float i01 = -(a01 * a22 - a02 * a21) * inv;
    const float i02 =  (a01 * a12 - a02 * a11) * inv;
    const float i10 = -(a10 * a22 - a12 * a20) * inv;
    const float i11 =  (a00 * a22 - a02 * a20) * inv;
    const float i12 = -(a00 * a12 - a02 * a10) * inv;
    const float i20 =  (a10 * a21 - a11 * a20) * inv;
    const float i21 = -(a00 * a21 - a01 * a20) * inv;
    const float i22 =  (a00 * a11 - a01 * a10) * inv;
    rx = i00 * gx + i01 * gy + i02;
    ry = i10 * gx + i11 * gy + i12;
    rz = i20 * gx + i21 * gy + i22;
}

__device__ inline int project_cell(float dep, float rx, float ry, float rz,
                                   float r00, float r01, float r02, float tx,
                                   float r10, float r11, float r12, float ty,
                                   float r20, float r21, float r22, float tz) {
    const float px = dep * rx, py = dep * ry, pz = dep * rz;
    const float x = r00 * px + r01 * py + r02 * pz + tx;
    const float y = r10 * px + r11 * py + r12 * pz + ty;
    const float z = r20 * px + r21 * py + r22 * pz + tz;
    const int bx = (int)((x - X_MIN) / RES_X);   // truncate-toward-zero == astype(int32)
    const int by = (int)((y - Y_MIN) / RES_Y);
    const bool valid = (bx >= 0) && (bx < BEV_W) && (by >= 0) && (by < BEV_H) && (z > 0.0f);
    return valid ? (by * BEV_W + bx) : -1;
}

// ---- K1: tiled transpose img[b,c,pix] -> img_t[b,pix,c] ----
__global__ __launch_bounds__(256) void k_transpose(const float* __restrict__ img,
                                                   float* __restrict__ img_t) {
    __shared__ float tile[32][33];
    const int b = blockIdx.z;
    const int tx = threadIdx.x, ty = threadIdx.y;      // block (32, 8)
    const int pix0 = blockIdx.x * 32, c0 = blockIdx.y * 32;
    #pragma unroll
    for (int j = 0; j < 32; j += 8)
        tile[ty + j][tx] = img[((size_t)(b * C_DIM + c0 + ty + j)) * HW + pix0 + tx];
    __syncthreads();
    #pragma unroll
    for (int j = 0; j < 32; j += 8)
        img_t[((size_t)(b * HW + pix0 + ty + j)) * C_DIM + c0 + tx] = tile[tx][ty + j];
}

// ---- K2: count merged runs per cell ----
__global__ __launch_bounds__(256) void k_count(const float* __restrict__ dv,
                                               const float* __restrict__ K,
                                               const float* __restrict__ T,
                                               int* __restrict__ hist) {
    const int tid = blockIdx.x * 256 + threadIdx.x;
    if (tid >= NPIX_TOT) return;
    const int b = tid / HW, pix = tid % HW;
    const int h = pix / IMG_W, w = pix % IMG_W;
    float rx, ry, rz;
    make_ray(K, b, (float)w, (float)h, rx, ry, rz);
    const float* Tb = T + b * 16;
    const float r00 = Tb[0], r01 = Tb[1], r02 = Tb[2],  tx = Tb[3];
    const float r10 = Tb[4], r11 = Tb[5], r12 = Tb[6],  ty = Tb[7];
    const float r20 = Tb[8], r21 = Tb[9], r22 = Tb[10], tz = Tb[11];
    int prev = -1;
    for (int d = 0; d < D_DIM; ++d) {
        const int cell = project_cell(dv[d], rx, ry, rz,
                                      r00, r01, r02, tx, r10, r11, r12, ty, r20, r21, r22, tz);
        if (cell != prev) {
            if (prev >= 0) atomicAdd(&hist[b * NCELL + prev], 1);
            prev = cell;
        }
    }
    if (prev >= 0) atomicAdd(&hist[b * NCELL + prev], 1);
}

// ---- K3: exclusive prefix scan over hist[32768] -> offs[32769], cursor ----
__global__ __launch_bounds__(1024) void k_scan(const int* __restrict__ hist,
                                               int* __restrict__ offs,
                                               int* __restrict__ cursor) {
    __shared__ int lds[1024];
    const int t = threadIdx.x;
    int h[32];
    int s = 0;
    const int base = t * 32;
    #pragma unroll
    for (int k = 0; k < 32; ++k) { h[k] = hist[base + k]; s += h[k]; }
    lds[t] = s;
    __syncthreads();
    for (int off = 1; off < 1024; off <<= 1) {
        int v = (t >= off) ? lds[t - off] : 0;
        __syncthreads();
        lds[t] += v;
        __syncthreads();
    }
    int run = lds[t] - s;   // exclusive base for this thread's chunk
    #pragma unroll
    for (int k = 0; k < 32; ++k) {
        offs[base + k] = run;
        cursor[base + k] = run;
        run += h[k];
    }
    if (t == 1023) offs[NCELL_TOT] = lds[1023];
}

// ---- K4: fill cell-bucketed entries: key = (gcell<<13)|pix, weight ----
__global__ __launch_bounds__(256) void k_fill(const float* __restrict__ dp,
                                              const float* __restrict__ dv,
                                              const float* __restrict__ K,
                                              const float* __restrict__ T,
                                              int* __restrict__ cursor,
                                              int* __restrict__ ekey,
                                              float* __restrict__ ew) {
    const int tid = blockIdx.x * 256 + threadIdx.x;
    if (tid >= NPIX_TOT) return;
    const int b = tid / HW, pix = tid % HW;
    const int h = pix / IMG_W, w = pix % IMG_W;
    float rx, ry, rz;
    make_ray(K, b, (float)w, (float)h, rx, ry, rz);
    const float* Tb = T + b * 16;
    const float r00 = Tb[0], r01 = Tb[1], r02 = Tb[2],  tx = Tb[3];
    const float r10 = Tb[4], r11 = Tb[5], r12 = Tb[6],  ty = Tb[7];
    const float r20 = Tb[8], r21 = Tb[9], r22 = Tb[10], tz = Tb[11];
    int prev = -1;
    float acc = 0.0f;
    for (int d = 0; d < D_DIM; ++d) {
        const int cell = project_cell(dv[d], rx, ry, rz,
                                      r00, r01, r02, tx, r10, r11, r12, ty, r20, r21, r22, tz);
        const float p = dp[((size_t)(b * D_DIM + d)) * HW + pix];
        if (cell == prev) {
            acc += p;
        } else {
            if (prev >= 0) {
                const int slot = atomicAdd(&cursor[b * NCELL + prev], 1);
                ekey[slot] = ((b * NCELL + prev) << 13) | pix;
                ew[slot] = acc;
            }
            prev = cell;
            acc = p;
        }
    }
    if (prev >= 0) {
        const int slot = atomicAdd(&cursor[b * NCELL + prev], 1);
        ekey[slot] = ((b * NCELL + prev) << 13) | pix;
        ew[slot] = acc;
    }
}

// ---- K5: chunked segmented reduction. Block = 64 entries, thread = channel. ----
__global__ __launch_bounds__(128) void k_chunk_gather(
    const float* __restrict__ img_t,
    const int* __restrict__ offs,     // offs[NCELL_TOT] = total entry count
    const int* __restrict__ ekey,
    const float* __restrict__ ew,
    float* __restrict__ out)
{
    const int total = offs[NCELL_TOT];
    const int base = blockIdx.x * CHUNK;
    if (base >= total) return;

    __shared__ int   s_key[CHUNK];
    __shared__ float s_w[CHUNK];
    if (threadIdx.x < CHUNK) {
        const int i = threadIdx.x;
        const int idx = min(base + i, total - 1);
        s_key[i] = ekey[idx];                                   // pad = dup of last key
        s_w[i]   = (base + i < total) ? ew[base + i] : 0.0f;    // pad weight 0 -> no-op
    }
    __syncthreads();

    const int c = threadIdx.x;
    int prev_gcell = s_key[0] >> 13;
    float acc = 0.0f;
    #pragma unroll 8
    for (int k = 0; k < CHUNK; ++k) {                // static trip count -> pipelined
        const int key = s_key[k];                    // LDS broadcast (wave-uniform)
        const int gcell = key >> 13;
        const int pix = key & 8191;
        const int b = gcell >> 14;
        const float v = img_t[((size_t)(b * HW + pix)) * C_DIM + c] * s_w[k];
        if (gcell != prev_gcell) {                   // wave-uniform branch
            const int pb = prev_gcell >> 14, pc = prev_gcell & (NCELL - 1);
            atomicAdd(&out[((size_t)(pb * C_DIM + c)) * NCELL + pc], acc);
            acc = 0.0f;
            prev_gcell = gcell;
        }
        acc += v;
    }
    const int pb = prev_gcell >> 14, pc = prev_gcell & (NCELL - 1);
    atomicAdd(&out[((size_t)(pb * C_DIM + c)) * NCELL + pc], acc);
}

extern "C" void kernel_launch(void* const* d_in, const int* in_sizes, int n_in,
                              void* d_out, int out_size, void* d_ws, size_t ws_size,
                              hipStream_t stream) {
    const float* img = (const float*)d_in[0];
    const float* dp  = (const float*)d_in[1];
    const float* dv  = (const float*)d_in[2];
    const float* K   = (const float*)d_in[3];
    const float* T   = (const float*)d_in[4];
    float* out = (float*)d_out;

    float* ws_f   = (float*)d_ws;
    float* img_t  = ws_f + WS_IMG_T;
    int*   hist   = (int*)d_ws + WS_HIST;
    int*   offs   = (int*)d_ws + WS_OFFS;
    int*   cursor = (int*)d_ws + WS_CURSOR;
    int*   ekey   = (int*)d_ws + WS_EKEY;
    float* ew     = ws_f + WS_EW;

    hipMemsetAsync(hist, 0, NCELL_TOT * sizeof(int), stream);
    hipMemsetAsync(out, 0, (size_t)out_size * sizeof(float), stream);

    k_transpose<<<dim3(HW / 32, C_DIM / 32, B_DIM), dim3(32, 8), 0, stream>>>(img, img_t);
    k_count<<<(NPIX_TOT + 255) / 256, 256, 0, stream>>>(dv, K, T, hist);
    k_scan<<<1, 1024, 0, stream>>>(hist, offs, cursor);
    k_fill<<<(NPIX_TOT + 255) / 256, 256, 0, stream>>>(dp, dv, K, T, cursor, ekey, ew);
    k_chunk_gather<<<MAX_ENTRIES / CHUNK, 128, 0, stream>>>(img_t, offs, ekey, ew, out);
}